// Round 6
// baseline (74.460 us; speedup 1.0000x reference)
//
#include <hip/hip_runtime.h>
#include <math.h>

#define N_ATOMS 512
#define N_MOL   16
#define HIDDEN  128
#define FILTERS 128
#define NUM_RBF 50
#define CUTOFF  10.0f
#define N_LAYERS 3

#define KBINS  1024              // lerp bins over [0, CUTOFF]
#define NBINS  (KBINS + 2)       // bins evaluated 0..1025 (>=1024 give env=0)
#define PROWS  (KBINS + 1)       // pair rows 0..1024; row k = {phi_k, phi_{k+1}} bf16
#define TOTW   (N_LAYERS * NBINS)        // 3078 table waves (one bin per wave)
#define TWBLK  ((TOTW + 7) / 8)          // 385 table blocks (8 waves each)
#define EMBB   8                         // emb blocks, 64 atoms each
#define PI_F   3.14159265358979f

__device__ __forceinline__ unsigned short f2bf(float v) {
    unsigned u = __float_as_uint(v);
    u += 0x7fffu + ((u >> 16) & 1u);     // round-to-nearest-even
    return (unsigned short)(u >> 16);
}
__device__ __forceinline__ float bf2f(unsigned short u) {
    return __uint_as_float((unsigned)u << 16);
}

// ============ front kernel: filter tables (1 bin per wave) ∥ embedding+xj0 ============
// Table role: wave w owns (layer, bin). rbf in registers (all lanes), h-row via
// wave-private LDS row, weights streamed as coalesced per-lane b32 loads.
// 3078 waves over 385 blocks -> ~12 waves/CU: latency hidden by TLP, no per-block
// 89KB weight-stream fixed cost (the R1..R5 table kernels' shared disease).
__global__ void __launch_bounds__(512) k_front(
        const int* __restrict__ an, const float* __restrict__ emb,
        const float* __restrict__ d1w, const float* __restrict__ d1b,
        const float* __restrict__ fw1, const float* __restrict__ fb1,
        const float* __restrict__ fw2, const float* __restrict__ fb2,
        float* __restrict__ x, unsigned short* __restrict__ xj,
        unsigned short* __restrict__ tab) {
    __shared__ float s_sh[8][HIDDEN];            // table: per-wave h row (4 KB)
    __shared__ __align__(16) float s_row[64][HIDDEN];  // emb rows (32 KB)
    __shared__ int   s_an[64];
    int bid = blockIdx.x, t = threadIdx.x;

    if (bid < TWBLK) {
        // ---------------- filter table ----------------
        int wv = t >> 6, lane = t & 63;
        int w  = bid * 8 + wv;
        int wc = w < TOTW ? w : TOTW - 1;        // clamp idle waves (uniform ctrl flow)
        int l  = wc / NBINS;
        int bin = wc - l * NBINS;
        float dd = bin * (CUTOFF / (float)KBINS);
        const float* w1g = fw1 + (size_t)l * NUM_RBF * FILTERS;
        const float* w2g = fw2 + (size_t)l * FILTERS * FILTERS;
        int c0 = lane, c1 = lane + 64;
        float h0 = fb1[l * FILTERS + c0];
        float h1 = fb1[l * FILTERS + c1];
        #pragma unroll 5
        for (int r = 0; r < NUM_RBF; r++) {
            float cr = r * (CUTOFF / (float)(NUM_RBF - 1));
            float xx = dd - cr;
            float rb = __expf(-xx * xx * 12.5f);          // 1/(2*w^2), w = 0.2
            h0 = fmaf(rb, w1g[r * FILTERS + c0], h0);
            h1 = fmaf(rb, w1g[r * FILTERS + c1], h1);
        }
        s_sh[wv][c0] = h0 / (1.f + __expf(-h0));          // silu
        s_sh[wv][c1] = h1 / (1.f + __expf(-h1));
        __syncthreads();
        float o0 = fb2[l * FILTERS + c0];
        float o1 = fb2[l * FILTERS + c1];
        #pragma unroll 4
        for (int hh = 0; hh < FILTERS; hh++) {
            float hv = s_sh[wv][hh];                      // LDS broadcast
            o0 = fmaf(hv, w2g[hh * FILTERS + c0], o0);
            o1 = fmaf(hv, w2g[hh * FILTERS + c1], o1);
        }
        float env = (bin >= KBINS) ? 0.f
                  : 0.5f * (__cosf(dd * (PI_F / CUTOFF)) + 1.f);
        unsigned short p0 = f2bf(o0 * env), p1 = f2bf(o1 * env);
        size_t base = (size_t)l * PROWS * FILTERS * 2;
        if (w < TOTW) {
            if (bin <= KBINS) {          // x-entry of row bin
                tab[base + ((size_t)bin * FILTERS + c0) * 2 + 0] = p0;
                tab[base + ((size_t)bin * FILTERS + c1) * 2 + 0] = p1;
            }
            if (bin >= 1) {              // y-entry of row bin-1
                tab[base + ((size_t)(bin - 1) * FILTERS + c0) * 2 + 1] = p0;
                tab[base + ((size_t)(bin - 1) * FILTERS + c1) * 2 + 1] = p1;
            }
        }
    } else {
        // ---------------- embedding gather + xj0 = x @ d1w[0] + d1b[0], 64 atoms ----------------
        int eb = bid - TWBLK;
        int i0 = eb * 64;
        if (t < 64) s_an[t] = an[i0 + t];
        __syncthreads();
        for (int idx = t; idx < 64 * HIDDEN; idx += 512) {
            int a = idx >> 7, c = idx & 127;
            float v = emb[(size_t)s_an[a] * HIDDEN + c];
            s_row[a][c] = v;
            x[(size_t)(i0 + a) * HIDDEN + c] = v;
        }
        __syncthreads();
        int cq = t & 31, ag = t >> 5;            // c = 4*cq+cc ; atoms ag*4+aa
        float o[4][4];
        float4 bv = *(const float4*)(d1b + 4 * cq);
        float bva[4] = { bv.x, bv.y, bv.z, bv.w };
        #pragma unroll
        for (int aa = 0; aa < 4; aa++)
            #pragma unroll
            for (int cc = 0; cc < 4; cc++) o[aa][cc] = bva[cc];
        #pragma unroll 4
        for (int h = 0; h < HIDDEN; h += 2) {
            float4 wA = *(const float4*)(d1w + (size_t)h * FILTERS + 4 * cq);
            float4 wB = *(const float4*)(d1w + (size_t)(h + 1) * FILTERS + 4 * cq);
            float wa[4] = { wA.x, wA.y, wA.z, wA.w };
            float wb[4] = { wB.x, wB.y, wB.z, wB.w };
            #pragma unroll
            for (int aa = 0; aa < 4; aa++) {
                float2 hp = *(const float2*)(&s_row[ag * 4 + aa][h]);   // broadcast b64
                #pragma unroll
                for (int cc = 0; cc < 4; cc++) {
                    o[aa][cc] = fmaf(hp.x, wa[cc], o[aa][cc]);
                    o[aa][cc] = fmaf(hp.y, wb[cc], o[aa][cc]);
                }
            }
        }
        #pragma unroll
        for (int aa = 0; aa < 4; aa++) {
            int i = i0 + ag * 4 + aa;
            #pragma unroll
            for (int cp = 0; cp < 2; cp++) {
                unsigned int pk = (unsigned)f2bf(o[aa][2 * cp]) |
                                  ((unsigned)f2bf(o[aa][2 * cp + 1]) << 16);
                *(unsigned int*)(xj + (size_t)i * FILTERS + 4 * cq + 2 * cp) = pk;
            }
        }
    }
}

// ======== fused layer: (kw build for l=0) + agg + x update + next xj; one j per block ========
// UNCHANGED from R5 (differential experiment: only front/pool rebuilt this round).
template<int FIRST, int LAST>
__global__ void __launch_bounds__(512) k_layer(const float* __restrict__ pos,
        float2* __restrict__ kw, const unsigned int* __restrict__ tab,
        const unsigned short* __restrict__ xj_in, float* __restrict__ x,
        const float* __restrict__ w2, const float* __restrict__ b2,
        const float* __restrict__ w1n, const float* __restrict__ b1n,
        unsigned short* __restrict__ xj_out) {
    int j = blockIdx.x;
    int t = threadIdx.x, f = t & 127, q = t >> 7;    // q in 0..3: i-quarter
    __shared__ float2 s_kw[N_ATOMS];
    __shared__ float  s_red[4][FILTERS];
    __shared__ float  s_agg[FILTERS];
    __shared__ float  s_xn[HIDDEN];
    __shared__ float  s_pos[FIRST ? N_ATOMS * 3 : 1];
    if (FIRST) {
        for (int idx = t; idx < N_ATOMS * 3; idx += 512) s_pos[idx] = pos[idx];
        __syncthreads();
        float pjx = s_pos[j*3+0], pjy = s_pos[j*3+1], pjz = s_pos[j*3+2];
        float dx = s_pos[t*3+0] - pjx;
        float dy = s_pos[t*3+1] - pjy;
        float dz = s_pos[t*3+2] - pjz;
        float d  = sqrtf(dx*dx + dy*dy + dz*dz);
        int   k; float w;
        if (t == j || d >= CUTOFF) { k = KBINS; w = 0.f; }   // all-zero pair row
        else {
            float tt = d * ((float)KBINS / CUTOFF);
            k = (int)tt;
            if (k > KBINS - 1) k = KBINS - 1;
            w = tt - (float)k;
        }
        float2 kv = make_float2(w, __int_as_float(k));
        s_kw[t] = kv;
        kw[(size_t)j * N_ATOMS + t] = kv;
        __syncthreads();
    } else {
        s_kw[t] = kw[(size_t)j * N_ATOMS + t];
        __syncthreads();
    }
    // ---- aggregation: each quarter sums 128 source atoms, 4 accumulators ----
    float acc0 = 0.f, acc1 = 0.f, acc2 = 0.f, acc3 = 0.f;
    int i0 = q * 128;
    #pragma unroll 2
    for (int ii = 0; ii < 128; ii += 4) {
        float2 kv0 = s_kw[i0 + ii];
        float2 kv1 = s_kw[i0 + ii + 1];
        float2 kv2 = s_kw[i0 + ii + 2];
        float2 kv3 = s_kw[i0 + ii + 3];
        unsigned int p0 = tab[(size_t)__float_as_int(kv0.y) * FILTERS + f];
        unsigned int p1 = tab[(size_t)__float_as_int(kv1.y) * FILTERS + f];
        unsigned int p2 = tab[(size_t)__float_as_int(kv2.y) * FILTERS + f];
        unsigned int p3 = tab[(size_t)__float_as_int(kv3.y) * FILTERS + f];
        float xv0 = bf2f(xj_in[(size_t)(i0 + ii    ) * FILTERS + f]);
        float xv1 = bf2f(xj_in[(size_t)(i0 + ii + 1) * FILTERS + f]);
        float xv2 = bf2f(xj_in[(size_t)(i0 + ii + 2) * FILTERS + f]);
        float xv3 = bf2f(xj_in[(size_t)(i0 + ii + 3) * FILTERS + f]);
        float lo0 = __uint_as_float(p0 << 16), hi0 = __uint_as_float(p0 & 0xffff0000u);
        float lo1 = __uint_as_float(p1 << 16), hi1 = __uint_as_float(p1 & 0xffff0000u);
        float lo2 = __uint_as_float(p2 << 16), hi2 = __uint_as_float(p2 & 0xffff0000u);
        float lo3 = __uint_as_float(p3 << 16), hi3 = __uint_as_float(p3 & 0xffff0000u);
        acc0 = fmaf(xv0, fmaf(kv0.x, hi0 - lo0, lo0), acc0);
        acc1 = fmaf(xv1, fmaf(kv1.x, hi1 - lo1, lo1), acc1);
        acc2 = fmaf(xv2, fmaf(kv2.x, hi2 - lo2, lo2), acc2);
        acc3 = fmaf(xv3, fmaf(kv3.x, hi3 - lo3, lo3), acc3);
    }
    s_red[q][f] = (acc0 + acc1) + (acc2 + acc3);
    __syncthreads();
    if (q == 0) s_agg[f] = s_red[0][f] + s_red[1][f] + s_red[2][f] + s_red[3][f];
    __syncthreads();
    // ---- x update: split the 128-term dot over quarters (32 each) ----
    float v = 0.f;
    int ff0 = q * 32;
    #pragma unroll 8
    for (int ff = ff0; ff < ff0 + 32; ff++) v = fmaf(s_agg[ff], w2[ff*HIDDEN + f], v);
    s_red[q][f] = v;
    __syncthreads();
    if (q == 0) {
        float xnew = x[j*HIDDEN + f] + b2[f] + s_red[0][f] + s_red[1][f] + s_red[2][f] + s_red[3][f];
        x[j*HIDDEN + f] = xnew;
        s_xn[f] = xnew;
    }
    __syncthreads();
    if (!LAST) {
        float a2 = 0.f;
        int h0 = q * 32;
        #pragma unroll 8
        for (int hh = h0; hh < h0 + 32; hh++) a2 = fmaf(s_xn[hh], w1n[hh*FILTERS + f], a2);
        s_red[q][f] = a2;
        __syncthreads();
        if (q == 0) xj_out[(size_t)j*FILTERS + f] =
            f2bf(b1n[f] + s_red[0][f] + s_red[1][f] + s_red[2][f] + s_red[3][f]);
    }
}

// ============ molecule pool + output MLP — fully parallel (no serial chains) ============
__global__ void __launch_bounds__(256) k_pool(const float* __restrict__ x,
        const int* __restrict__ batch, const float* __restrict__ ow1,
        const float* __restrict__ ob1, const float* __restrict__ ow2,
        const float* __restrict__ ob2, float* __restrict__ out) {
    int m = blockIdx.x, t = threadIdx.x;
    __shared__ float s_red[2][FILTERS];
    __shared__ float s_mol[HIDDEN];
    __shared__ float s_hh[64];
    __shared__ int   s_lo, s_cnt;
    if (t == 0) { s_lo = 0; s_cnt = 0; }
    __syncthreads();
    {   // parallel segment bounds on the sorted batch array
        int b0 = batch[t], b1 = batch[t + 256];
        int mylo  = (b0 <  m) + (b1 <  m);
        int mycnt = (b0 == m) + (b1 == m);
        atomicAdd(&s_lo, mylo);              // wave-coalesced by compiler
        atomicAdd(&s_cnt, mycnt);
    }
    __syncthreads();
    int lo = s_lo, cnt = s_cnt, hi = lo + cnt;
    // parallel row sum
    int f = t & 127, half = t >> 7;
    float s = 0.f;
    for (int i = lo + half; i < hi; i += 2) s += x[(size_t)i * HIDDEN + f];
    s_red[half][f] = s;
    __syncthreads();
    if (half == 0) s_mol[f] = (s_red[0][f] + s_red[1][f]) / (float)(cnt > 0 ? cnt : 1);
    __syncthreads();
    // MLP1: 64 outputs x 4 slices of 32 terms
    int o = t & 63, sl = t >> 6;
    float a = 0.f;
    #pragma unroll 8
    for (int h = sl * 32; h < sl * 32 + 32; h++) a = fmaf(s_mol[h], ow1[h * 64 + o], a);
    float* sr = (float*)s_red;               // reuse as [4][64]
    __syncthreads();
    sr[sl * 64 + o] = a;
    __syncthreads();
    if (t < 64) {
        float v = ob1[t] + sr[t] + sr[64 + t] + sr[128 + t] + sr[192 + t];
        s_hh[t] = v / (1.f + __expf(-v));    // silu
    }
    __syncthreads();
    if (t < 64) {                            // wave 0: parallel 64-term dot
        float v = s_hh[t] * ow2[t];
        for (int off = 32; off > 0; off >>= 1) v += __shfl_down(v, off, 64);
        if (t == 0) out[m] = v + ob2[0];
    }
}

extern "C" void kernel_launch(void* const* d_in, const int* in_sizes, int n_in,
                              void* d_out, int out_size, void* d_ws, size_t ws_size,
                              hipStream_t stream) {
    const int*   an    = (const int*)  d_in[0];
    const float* pos   = (const float*)d_in[1];
    const int*   batch = (const int*)  d_in[2];
    const float* emb   = (const float*)d_in[3];
    const float* fw1   = (const float*)d_in[4];
    const float* fb1   = (const float*)d_in[5];
    const float* fw2   = (const float*)d_in[6];
    const float* fb2   = (const float*)d_in[7];
    const float* d1w   = (const float*)d_in[8];
    const float* d1b   = (const float*)d_in[9];
    const float* d2w   = (const float*)d_in[10];
    const float* d2b   = (const float*)d_in[11];
    const float* ow1   = (const float*)d_in[12];
    const float* ob1   = (const float*)d_in[13];
    const float* ow2   = (const float*)d_in[14];
    const float* ob2   = (const float*)d_in[15];
    float* out = (float*)d_out;

    float*          ws   = (float*)d_ws;
    float2*         kw   = (float2*)ws;                                    // 2 MB
    float*          x    = (float*)(kw + (size_t)N_ATOMS * N_ATOMS);       // 256 KB
    unsigned short* xjA  = (unsigned short*)(x + N_ATOMS * HIDDEN);        // 128 KB
    unsigned short* xjB  = xjA + (size_t)N_ATOMS * FILTERS;                // 128 KB
    unsigned short* tab  = xjB + (size_t)N_ATOMS * FILTERS;                // 1.575 MB

    k_front<<<TWBLK + EMBB, 512, 0, stream>>>(
        an, emb, d1w, d1b, fw1, fb1, fw2, fb2, x, xjA, tab);

    const unsigned int* t0 = (const unsigned int*)(tab + (size_t)0 * PROWS * FILTERS * 2);
    const unsigned int* t1 = (const unsigned int*)(tab + (size_t)1 * PROWS * FILTERS * 2);
    const unsigned int* t2 = (const unsigned int*)(tab + (size_t)2 * PROWS * FILTERS * 2);

    k_layer<1,0><<<N_ATOMS, 512, 0, stream>>>(pos, kw, t0, xjA, x,
        d2w + (size_t)0*FILTERS*HIDDEN, d2b + (size_t)0*HIDDEN,
        d1w + (size_t)1*HIDDEN*FILTERS, d1b + (size_t)1*FILTERS, xjB);
    k_layer<0,0><<<N_ATOMS, 512, 0, stream>>>(pos, kw, t1, xjB, x,
        d2w + (size_t)1*FILTERS*HIDDEN, d2b + (size_t)1*HIDDEN,
        d1w + (size_t)2*HIDDEN*FILTERS, d1b + (size_t)2*FILTERS, xjA);
    k_layer<0,1><<<N_ATOMS, 512, 0, stream>>>(pos, kw, t2, xjA, x,
        d2w + (size_t)2*FILTERS*HIDDEN, d2b + (size_t)2*HIDDEN,
        d1w, d1b, xjB);

    k_pool<<<N_MOL, 256, 0, stream>>>(x, batch, ow1, ob1, ow2, ob2, out);
}